// Round 7
// baseline (544.368 us; speedup 1.0000x reference)
//
#include <hip/hip_runtime.h>
#include <hip/hip_bf16.h>

#define NB 16384
#define NZ 128
#define NH 512
#define NHID 512
#define NT 32

typedef __attribute__((ext_vector_type(8))) short short8;
typedef __attribute__((ext_vector_type(4))) short short4v;
typedef __attribute__((ext_vector_type(4))) float f32x4;
typedef __attribute__((ext_vector_type(2))) long long2v;

__device__ __forceinline__ short f2bf(float x) {
    union { __hip_bfloat16 h; short s; } u; u.h = __float2bfloat16(x); return u.s;
}
__device__ __forceinline__ float bf2f(short s) {
    union { unsigned int u; float f; } v; v.u = ((unsigned int)(unsigned short)s) << 16; return v.f;
}

// ---------------------------------------------------------------------------
// Prologue pack:
//  w1aT  bf16 A-frags [ht(32)][kt(4)]   (128 frags x 1KB)
//  w2T8  fp8  A-frags [kt2(16)][jt(8)]  (128 frags x 512B)
//  w1bT  bf16 A-frags [ht(32)][kt(16)]  (512 frags x 1KB)
// A-frag 16x16x32: lane l holds A[m=l&15][k=(l>>4)*8+j], j=0..7.
// ---------------------------------------------------------------------------
__global__ __launch_bounds__(64) void pack_weights(const float* __restrict__ W1,
                                                   const float* __restrict__ W2,
                                                   short* __restrict__ w1aT,
                                                   long* __restrict__ w2T8,
                                                   short* __restrict__ w1bT) {
    int f = blockIdx.x;
    int l = threadIdx.x;
    int quad = l >> 4, m = l & 15;
    if (f < 128) {                       // W1a^T : A[h][k] = W1[k][h], k<128
        int ht = f >> 2, kt = f & 3;
        short8 o;
#pragma unroll
        for (int j = 0; j < 8; ++j)
            o[j] = f2bf(W1[(size_t)(kt * 32 + quad * 8 + j) * NH + ht * 16 + m]);
        *(short8*)(w1aT + ((size_t)f * 64 + l) * 8) = o;
    } else if (f < 256) {                // W2^T fp8 : A[j][k=h] = W2[h][j]
        int g = f - 128; int kt2 = g >> 3, jt = g & 7;
        float v[8];
#pragma unroll
        for (int j = 0; j < 8; ++j)
            v[j] = W2[(size_t)(kt2 * 32 + quad * 8 + j) * NZ + jt * 16 + m];
        int lo = __builtin_amdgcn_cvt_pk_fp8_f32(v[0], v[1], 0, false);
        lo = __builtin_amdgcn_cvt_pk_fp8_f32(v[2], v[3], lo, true);
        int hi = __builtin_amdgcn_cvt_pk_fp8_f32(v[4], v[5], 0, false);
        hi = __builtin_amdgcn_cvt_pk_fp8_f32(v[6], v[7], hi, true);
        long pv = ((long)(unsigned int)hi << 32) | (unsigned int)lo;
        w2T8[(size_t)g * 64 + l] = pv;
    } else {                             // W1b^T : A[h][k] = W1[128+k][h]
        int g = f - 256; int ht = g >> 4, kt = g & 15;
        short8 o;
#pragma unroll
        for (int j = 0; j < 8; ++j)
            o[j] = f2bf(W1[(size_t)(128 + kt * 32 + quad * 8 + j) * NH + ht * 16 + m]);
        *(short8*)(w1bT + ((size_t)g * 64 + l) * 8) = o;
    }
}

// ---------------------------------------------------------------------------
// Main: 256 blocks x 512 thr (8 waves), 64 rows/block. Round-5 structure
// (241us: paired-kt2 hid, rs-chunked GEMM1, reg-resident EW, 2 barriers)
// + deferred-scaling EW math ONLY (round-6 verified correct):
//   pd = SUM t2^2 folded once/step by -0.5/sb^2 (scb[3]);
//   pe = SUM e^2 folded ONCE at end by 0.5 (t-invariant coeff);
//   per-elem +sca3 -> precomputed 16*sca3 once/step (scb[4]).
//   Exact re-association of the same fp32 math (absmax 0.0 in round 6).
//
// INLINE-ASM LAW (round-6 post-mortem, = guide m240): do NOT hand-write
// v_cvt_pk_bf16_f32 for the z-publish. The asm black-box serialized the EW
// tail (+34us pure stall, VALU busy actually fell). Scalar f2bf casts let
// the compiler schedule conversions into the fma chains.
//
// REGISTER-CLIFF LAW (rounds 1/3): kernel sits at the 128-arch-VGPR limit.
// Do NOT extend liveness across a GEMM phase; do NOT use launch_bounds(,4).
// Occupancy pinned at 2 waves/SIMD by arch+acc pressure (round 2).
//
// LDS 49KB: zu[4][16][256B] bf16 z | hid[4][16][512B] fp8 paired-kt2 |
// sconst[32][8]f32. Spill guard: FETCH ~165.5MB, WRITE ~5.2MB.
// ---------------------------------------------------------------------------
__global__ __launch_bounds__(512, 2) void diffusion_main(
    const float* __restrict__ eps0, const float* __restrict__ eps,
    const float* __restrict__ beta, const float* __restrict__ sigma0,
    const float* __restrict__ ctx, const float* __restrict__ b1,
    const float* __restrict__ b2, const float* __restrict__ t_emb,
    const float* __restrict__ target_mu,
    const short* __restrict__ w1aT, const short* __restrict__ w1bT,
    const long* __restrict__ w2T8, float* __restrict__ out)
{
    __shared__ alignas(16) char lds[50176];
    char* zu = lds;                      // 16 KB
    char* hidb = lds + 16384;            // 32 KB
    float* scb = (float*)(lds + 49152);  // 1 KB step constants
    const int w = threadIdx.x >> 6;
    const int lane = threadIdx.x & 63;
    const int quad = lane >> 4;
    const int m = lane & 15;
    const int swz = m & 7;
    const int rowbase = blockIdx.x * 64;
    const int jcol = w * 16 + quad * 4;  // this lane's u/z columns (EW layout)
    const float dt = 1.0f / 32.0f;
    const float s0 = sigma0[0];
    const float logs0 = logf(s0);
    const f32x4 zero = {0.f, 0.f, 0.f, 0.f};

    // XOR-swizzle address bases (per-lane constants)
    const int zu_base = m * 256 + ((quad ^ swz) << 4);   // GEMM1 z read: ^ (kt<<6), +rs*4096
    const int hw_base = m * 512 + ((quad & 1) << 2);     // hid write: + Gc, +rs*8192
    const int hr_base = m * 512;                         // hid read: +((4kp+quad)^m)<<4, +rs*8192
    const int zw_off  = m * 256 + ((((w << 1) + (quad >> 1)) ^ swz) << 4)
                      + ((quad & 1) << 3);               // EW z write (u-layout), +rs*4096

    // step constants (computed once):
    // [0]=beta_f  [1]=sf  [2]=c1mb(1-bb*dt)  [3]=-0.5/sb^2  [4]=16*0.5*(ln bf - ln bb)
    if (threadIdx.x < 32) {
        int t = threadIdx.x;
        float bfv = beta[t];
        float bbv = beta[(t + 31) & 31];
        float sf = sqrtf(2.f * bfv * dt) * s0;
        float sb = sqrtf(2.f * bbv * dt) * s0;
        scb[t * 8 + 0] = bfv;
        scb[t * 8 + 1] = sf;
        scb[t * 8 + 2] = 1.f - bbv * dt;
        scb[t * 8 + 3] = -0.5f / (sb * sb);
        scb[t * 8 + 4] = 8.f * (logf(bfv) - logf(bbv));
    }

    // ---- prologue: cbr[c][rs] = (ctx @ W1b + b1), this wave's 4 h-tiles ----
    f32x4 pacc[4][4];
#pragma unroll
    for (int c = 0; c < 4; ++c)
#pragma unroll
        for (int rs = 0; rs < 4; ++rs) pacc[c][rs] = zero;
#pragma unroll 4
    for (int kt = 0; kt < 16; ++kt) {
        short8 cf[4];
#pragma unroll
        for (int rs = 0; rs < 4; ++rs) {
            const float* cp = ctx + (size_t)(rowbase + rs * 16 + m) * NH + kt * 32 + quad * 8;
            f32x4 a = *(const f32x4*)cp;
            f32x4 b = *(const f32x4*)(cp + 4);
            short8 tt;
#pragma unroll
            for (int j = 0; j < 4; ++j) { tt[j] = f2bf(a[j]); tt[4 + j] = f2bf(b[j]); }
            cf[rs] = tt;
        }
#pragma unroll
        for (int c = 0; c < 4; ++c) {
            short8 af = *(const short8*)(w1bT + ((size_t)((w * 4 + c) * 16 + kt) * 64 + lane) * 8);
#pragma unroll
            for (int rs = 0; rs < 4; ++rs)
                pacc[c][rs] = __builtin_amdgcn_mfma_f32_16x16x32_bf16(af, cf[rs], pacc[c][rs], 0, 0, 0);
        }
    }
    short4v cbr[4][4];
#pragma unroll
    for (int c = 0; c < 4; ++c) {
        f32x4 bv = *(const f32x4*)(b1 + (w * 4 + c) * 16 + quad * 4);
#pragma unroll
        for (int rs = 0; rs < 4; ++rs) {
            short4v o;
#pragma unroll
            for (int i = 0; i < 4; ++i) o[i] = f2bf(pacc[c][rs][i] + bv[i]);
            cbr[c][rs] = o;
        }
    }
    f32x4 b2r = *(const f32x4*)(b2 + jcol);  // b2 for this lane's EW columns

    // ---- persistent weights into registers ----
    short8 wf1[4][4];
#pragma unroll
    for (int c = 0; c < 4; ++c)
#pragma unroll
        for (int kt = 0; kt < 4; ++kt)
            wf1[c][kt] = *(const short8*)(w1aT + ((size_t)((w * 4 + c) * 4 + kt) * 64 + lane) * 8);
    long wf2[16];
#pragma unroll
    for (int kt2 = 0; kt2 < 16; ++kt2)
        wf2[kt2] = w2T8[(size_t)(kt2 * 8 + w) * 64 + lane];

    // ---- init own z slice (u-layout: rows rs*16+m, cols jcol..jcol+3) ----
    float zr[4][4];
    float part = 0.f;
    float pe = 0.f;        // SUM e^2 across all steps; folded by 0.5 at end
#pragma unroll
    for (int rs = 0; rs < 4; ++rs) {
        f32x4 e = *(const f32x4*)(eps0 + (size_t)(rowbase + rs * 16 + m) * NZ + jcol);
        short4v zb;
#pragma unroll
        for (int i = 0; i < 4; ++i) { zr[rs][i] = s0 * e[i]; zb[i] = f2bf(zr[rs][i]); }
        *(short4v*)(zu + rs * 4096 + zw_off) = zb;
    }
    __syncthreads();   // A (initial)

#pragma unroll 1
    for (int t = 0; t < NT; ++t) {
        // ---- GEMM1 (bf16, weights in regs): 2 chunks of 2 ROWSETS ----
        // Each z-frag read exactly once; 4:1 MFMA:LDS-read ratio.
#pragma unroll
        for (int rr = 0; rr < 2; ++rr) {
            f32x4 g1[4][2];
#pragma unroll
            for (int c = 0; c < 4; ++c)
#pragma unroll
                for (int r2 = 0; r2 < 2; ++r2) g1[c][r2] = zero;
#pragma unroll
            for (int kt = 0; kt < 4; ++kt) {
                short8 zb[2];
#pragma unroll
                for (int r2 = 0; r2 < 2; ++r2)
                    zb[r2] = *(const short8*)(zu + (rr * 2 + r2) * 4096 + (zu_base ^ (kt << 6)));
#pragma unroll
                for (int c = 0; c < 4; ++c)
#pragma unroll
                    for (int r2 = 0; r2 < 2; ++r2)
                        g1[c][r2] = __builtin_amdgcn_mfma_f32_16x16x32_bf16(
                            wf1[c][kt], zb[r2], g1[c][r2], 0, 0, 0);
            }
#pragma unroll
            for (int c = 0; c < 4; ++c) {
                // paired-kt2 granule address for h-tile ht=4w+c (round-3/4 verified)
                int Gc = (((w * 4 + ((c & 1) << 1) + (quad >> 1)) ^ m) << 4)
                       + (((c >> 1) & 1) << 3);
                f32x4 te = *(const f32x4*)(t_emb + (size_t)t * NHID + (w * 4 + c) * 16 + quad * 4);
#pragma unroll
                for (int r2 = 0; r2 < 2; ++r2) {
                    int rs = rr * 2 + r2;
                    float p0 = fmaxf(g1[c][r2][0] + bf2f(cbr[c][rs][0]) + te[0], 0.f);
                    float p1 = fmaxf(g1[c][r2][1] + bf2f(cbr[c][rs][1]) + te[1], 0.f);
                    float p2 = fmaxf(g1[c][r2][2] + bf2f(cbr[c][rs][2]) + te[2], 0.f);
                    float p3 = fmaxf(g1[c][r2][3] + bf2f(cbr[c][rs][3]) + te[3], 0.f);
                    int pk = __builtin_amdgcn_cvt_pk_fp8_f32(p0, p1, 0, false);
                    pk = __builtin_amdgcn_cvt_pk_fp8_f32(p2, p3, pk, true);
                    *(int*)(hidb + rs * 8192 + hw_base + Gc) = pk;
                }
            }
        }
        __syncthreads();   // B: hid ready

        // eps prefetch (u-layout rows) — latency hides under GEMM2
        f32x4 ef[4];
        {
            const float* ept = eps + (size_t)t * NB * NZ + (size_t)rowbase * NZ + jcol;
#pragma unroll
            for (int rs = 0; rs < 4; ++rs)
                ef[rs] = *(const f32x4*)(ept + (size_t)(rs * 16 + m) * NZ);
        }
        f32x4 sca = *(const f32x4*)(scb + t * 8);   // bf, sf, c1mb, -0.5/sb^2
        float s_l = scb[t * 8 + 4];                 // 16*sca3

        // ---- GEMM2 (fp8, weights in regs): j-tile jt=w, paired-kt2 b128 reads ----
        f32x4 ua[4];
#pragma unroll
        for (int rs = 0; rs < 4; ++rs) ua[rs] = zero;
#pragma unroll
        for (int kp = 0; kp < 8; ++kp) {
            long wlo = wf2[kp * 2];
            long whi = wf2[kp * 2 + 1];
            int go = ((kp * 4 + quad) ^ m) << 4;
#pragma unroll
            for (int rs = 0; rs < 4; ++rs) {
                long2v h2 = *(const long2v*)(hidb + rs * 8192 + hr_base + go);
                ua[rs] = __builtin_amdgcn_mfma_f32_16x16x32_fp8_fp8(wlo, h2[0], ua[rs], 0, 0, 0);
                ua[rs] = __builtin_amdgcn_mfma_f32_16x16x32_fp8_fp8(whi, h2[1], ua[rs], 0, 0, 0);
            }
        }

        // ---- elementwise, fully in registers; deferred scalings, scalar casts ----
        float pdA = 0.f, pdB = 0.f;
#pragma unroll
        for (int rs = 0; rs < 4; ++rs) {
            short4v zb;
#pragma unroll
            for (int i = 0; i < 4; ++i) {
                float z = zr[rs][i];
                float e = ef[rs][i];
                float uu = ua[rs][i] + b2r[i];
                float t1 = fmaf(sca[0], z, uu);
                float zn = fmaf(t1, dt, z);
                zn = fmaf(sca[1], e, zn);
                float t2 = fmaf(-sca[2], zn, z);
                if (rs < 2) pdA = fmaf(t2, t2, pdA); else pdB = fmaf(t2, t2, pdB);
                pe = fmaf(e, e, pe);
                zr[rs][i] = zn;
                zb[i] = f2bf(zn);
            }
            *(short4v*)(zu + rs * 4096 + zw_off) = zb;
        }
        part = fmaf(sca[3], pdA + pdB, part);
        part += s_l;
        __syncthreads();   // A: z published for next step
    }

    // fold deferred 0.5*SUM e^2
    part = fmaf(0.5f, pe, part);

    // ---- terminal + prior correction: (z0/s0) == eps0 exactly ----
#pragma unroll
    for (int rs = 0; rs < 4; ++rs) {
        const float* ep = eps0 + (size_t)(rowbase + rs * 16 + m) * NZ + jcol;
        const float* tp = target_mu + (size_t)(rowbase + rs * 16 + m) * NZ + jcol;
        f32x4 a = *(const f32x4*)ep;
        f32x4 ta = *(const f32x4*)tp;
#pragma unroll
        for (int i = 0; i < 4; ++i) {
            float d0 = zr[rs][i] - ta[i];
            part += -0.5f * d0 * d0 + 0.5f * a[i] * a[i] + logs0;
        }
    }
#pragma unroll
    for (int off = 32; off >= 1; off >>= 1) part += __shfl_xor(part, off, 64);
    if (lane == 0) atomicAdd(out, part * (1.0f / NB));
}

extern "C" void kernel_launch(void* const* d_in, const int* in_sizes, int n_in,
                              void* d_out, int out_size, void* d_ws, size_t ws_size,
                              hipStream_t stream) {
    const float* ctx  = (const float*)d_in[0];
    const float* eps0 = (const float*)d_in[1];
    const float* eps  = (const float*)d_in[2];
    const float* beta = (const float*)d_in[3];
    const float* sig0 = (const float*)d_in[4];
    const float* W1   = (const float*)d_in[5];
    const float* b1   = (const float*)d_in[6];
    const float* W2   = (const float*)d_in[7];
    const float* b2   = (const float*)d_in[8];
    const float* temb = (const float*)d_in[9];
    const float* tmu  = (const float*)d_in[10];
    float* out = (float*)d_out;

    char* ws = (char*)d_ws;
    short* w1aT = (short*)ws;                  // 131072 B
    long*  w2T8 = (long*)(ws + 131072);        //  65536 B (fp8 frags)
    short* w1bT = (short*)(ws + 196608);       // 524288 B

    hipMemsetAsync(d_out, 0, sizeof(float), stream);
    pack_weights<<<768, 64, 0, stream>>>(W1, W2, w1aT, w2T8, w1bT);
    diffusion_main<<<256, 512, 0, stream>>>(eps0, eps, beta, sig0, ctx, b1, b2,
                                            temb, tmu, w1aT, w1bT, w2T8, out);
}

// Round 8
// 529.538 us; speedup vs baseline: 1.0280x; 1.0280x over previous
//
#include <hip/hip_runtime.h>
#include <hip/hip_bf16.h>

#define NB 16384
#define NZ 128
#define NH 512
#define NHID 512
#define NT 32

typedef __attribute__((ext_vector_type(8))) short short8;
typedef __attribute__((ext_vector_type(4))) short short4v;
typedef __attribute__((ext_vector_type(4))) float f32x4;
typedef __attribute__((ext_vector_type(2))) long long2v;

__device__ __forceinline__ short f2bf(float x) {
    union { __hip_bfloat16 h; short s; } u; u.h = __float2bfloat16(x); return u.s;
}
__device__ __forceinline__ float bf2f(short s) {
    union { unsigned int u; float f; } v; v.u = ((unsigned int)(unsigned short)s) << 16; return v.f;
}

// ---------------------------------------------------------------------------
// Prologue pack:
//  w1aT  bf16 A-frags [ht(32)][kt(4)]   (128 frags x 1KB)
//  w2T8  fp8  A-frags [kt2(16)][jt(8)]  (128 frags x 512B)
//  w1bT  bf16 A-frags [ht(32)][kt(16)]  (512 frags x 1KB)
// A-frag 16x16x32: lane l holds A[m=l&15][k=(l>>4)*8+j], j=0..7.
// ---------------------------------------------------------------------------
__global__ __launch_bounds__(64) void pack_weights(const float* __restrict__ W1,
                                                   const float* __restrict__ W2,
                                                   short* __restrict__ w1aT,
                                                   long* __restrict__ w2T8,
                                                   short* __restrict__ w1bT) {
    int f = blockIdx.x;
    int l = threadIdx.x;
    int quad = l >> 4, m = l & 15;
    if (f < 128) {                       // W1a^T : A[h][k] = W1[k][h], k<128
        int ht = f >> 2, kt = f & 3;
        short8 o;
#pragma unroll
        for (int j = 0; j < 8; ++j)
            o[j] = f2bf(W1[(size_t)(kt * 32 + quad * 8 + j) * NH + ht * 16 + m]);
        *(short8*)(w1aT + ((size_t)f * 64 + l) * 8) = o;
    } else if (f < 256) {                // W2^T fp8 : A[j][k=h] = W2[h][j]
        int g = f - 128; int kt2 = g >> 3, jt = g & 7;
        float v[8];
#pragma unroll
        for (int j = 0; j < 8; ++j)
            v[j] = W2[(size_t)(kt2 * 32 + quad * 8 + j) * NZ + jt * 16 + m];
        int lo = __builtin_amdgcn_cvt_pk_fp8_f32(v[0], v[1], 0, false);
        lo = __builtin_amdgcn_cvt_pk_fp8_f32(v[2], v[3], lo, true);
        int hi = __builtin_amdgcn_cvt_pk_fp8_f32(v[4], v[5], 0, false);
        hi = __builtin_amdgcn_cvt_pk_fp8_f32(v[6], v[7], hi, true);
        long pv = ((long)(unsigned int)hi << 32) | (unsigned int)lo;
        w2T8[(size_t)g * 64 + l] = pv;
    } else {                             // W1b^T : A[h][k] = W1[128+k][h]
        int g = f - 256; int ht = g >> 4, kt = g & 15;
        short8 o;
#pragma unroll
        for (int j = 0; j < 8; ++j)
            o[j] = f2bf(W1[(size_t)(128 + kt * 32 + quad * 8 + j) * NH + ht * 16 + m]);
        *(short8*)(w1bT + ((size_t)g * 64 + l) * 8) = o;
    }
}

// ---------------------------------------------------------------------------
// Main: 256 blocks x 512 thr (8 waves), 64 rows/block. Round-5 revert
// (241us verified: paired-kt2 hid, rs-chunked GEMM1, reg-resident EW,
// 2 barriers, round-5 EW math) + ONE pressure-REDUCING restructure:
// GEMM2 fused with EW per ROWSET-PAIR (rp loop):
//   - ua liveness 16 -> 8 VGPRs (frees allocator at the 128-cap);
//   - rp=0's EW (pure VALU) overlaps rp=1's MFMAs (separate pipes, m114);
//   - pair granularity keeps 2 interleaved MFMA acc chains/wave so the
//     fp8 chain stays issue-bound, not latency-bound.
//
// EW-MICRO-OPT LAW (rounds 6/7 post-mortem): do NOT add persistent
// accumulators (pe) or inline-asm cvt_pk to the EW; both lost 20-34us at
// the register cliff despite less VALU work. Round-5 EW math is the
// verified optimum of this structure.
// REGISTER-CLIFF LAW (rounds 1/3): 128-arch-VGPR limit. Do NOT extend
// liveness across a GEMM phase; do NOT use launch_bounds(,4). Occupancy
// pinned at 2 waves/SIMD (round 2); grid games don't move it.
//
// LDS 49KB: zu[4][16][256B] bf16 z | hid[4][16][512B] fp8 paired-kt2 |
// sconst[32][8]f32. Spill guard: FETCH ~165.5MB, WRITE ~5.2MB.
// ---------------------------------------------------------------------------
__global__ __launch_bounds__(512, 2) void diffusion_main(
    const float* __restrict__ eps0, const float* __restrict__ eps,
    const float* __restrict__ beta, const float* __restrict__ sigma0,
    const float* __restrict__ ctx, const float* __restrict__ b1,
    const float* __restrict__ b2, const float* __restrict__ t_emb,
    const float* __restrict__ target_mu,
    const short* __restrict__ w1aT, const short* __restrict__ w1bT,
    const long* __restrict__ w2T8, float* __restrict__ out)
{
    __shared__ alignas(16) char lds[50176];
    char* zu = lds;                      // 16 KB
    char* hidb = lds + 16384;            // 32 KB
    float* scb = (float*)(lds + 49152);  // 1 KB step constants
    const int w = threadIdx.x >> 6;
    const int lane = threadIdx.x & 63;
    const int quad = lane >> 4;
    const int m = lane & 15;
    const int swz = m & 7;
    const int rowbase = blockIdx.x * 64;
    const int jcol = w * 16 + quad * 4;  // this lane's u/z columns (EW layout)
    const float dt = 1.0f / 32.0f;
    const float s0 = sigma0[0];
    const float logs0 = logf(s0);
    const f32x4 zero = {0.f, 0.f, 0.f, 0.f};

    // XOR-swizzle address bases (per-lane constants)
    const int zu_base = m * 256 + ((quad ^ swz) << 4);   // GEMM1 z read: ^ (kt<<6), +rs*4096
    const int hw_base = m * 512 + ((quad & 1) << 2);     // hid write: + Gc, +rs*8192
    const int hr_base = m * 512;                         // hid read: +((4kp+quad)^m)<<4, +rs*8192
    const int zw_off  = m * 256 + ((((w << 1) + (quad >> 1)) ^ swz) << 4)
                      + ((quad & 1) << 3);               // EW z write (u-layout), +rs*4096

    // step constants (round-5 layout):
    // [0]=beta_f  [1]=sf  [2]=1/sb  [3]=0.5*(ln bf - ln bb)  [4]=1-bb*dt
    if (threadIdx.x < 32) {
        int t = threadIdx.x;
        float bfv = beta[t];
        float bbv = beta[(t + 31) & 31];
        float sf = sqrtf(2.f * bfv * dt) * s0;
        float sb = sqrtf(2.f * bbv * dt) * s0;
        scb[t * 8 + 0] = bfv;
        scb[t * 8 + 1] = sf;
        scb[t * 8 + 2] = 1.f / sb;
        scb[t * 8 + 3] = 0.5f * (logf(bfv) - logf(bbv));
        scb[t * 8 + 4] = 1.f - bbv * dt;
    }

    // ---- prologue: cbr[c][rs] = (ctx @ W1b + b1), this wave's 4 h-tiles ----
    f32x4 pacc[4][4];
#pragma unroll
    for (int c = 0; c < 4; ++c)
#pragma unroll
        for (int rs = 0; rs < 4; ++rs) pacc[c][rs] = zero;
#pragma unroll 4
    for (int kt = 0; kt < 16; ++kt) {
        short8 cf[4];
#pragma unroll
        for (int rs = 0; rs < 4; ++rs) {
            const float* cp = ctx + (size_t)(rowbase + rs * 16 + m) * NH + kt * 32 + quad * 8;
            f32x4 a = *(const f32x4*)cp;
            f32x4 b = *(const f32x4*)(cp + 4);
            short8 tt;
#pragma unroll
            for (int j = 0; j < 4; ++j) { tt[j] = f2bf(a[j]); tt[4 + j] = f2bf(b[j]); }
            cf[rs] = tt;
        }
#pragma unroll
        for (int c = 0; c < 4; ++c) {
            short8 af = *(const short8*)(w1bT + ((size_t)((w * 4 + c) * 16 + kt) * 64 + lane) * 8);
#pragma unroll
            for (int rs = 0; rs < 4; ++rs)
                pacc[c][rs] = __builtin_amdgcn_mfma_f32_16x16x32_bf16(af, cf[rs], pacc[c][rs], 0, 0, 0);
        }
    }
    short4v cbr[4][4];
#pragma unroll
    for (int c = 0; c < 4; ++c) {
        f32x4 bv = *(const f32x4*)(b1 + (w * 4 + c) * 16 + quad * 4);
#pragma unroll
        for (int rs = 0; rs < 4; ++rs) {
            short4v o;
#pragma unroll
            for (int i = 0; i < 4; ++i) o[i] = f2bf(pacc[c][rs][i] + bv[i]);
            cbr[c][rs] = o;
        }
    }
    f32x4 b2r = *(const f32x4*)(b2 + jcol);  // b2 for this lane's EW columns

    // ---- persistent weights into registers ----
    short8 wf1[4][4];
#pragma unroll
    for (int c = 0; c < 4; ++c)
#pragma unroll
        for (int kt = 0; kt < 4; ++kt)
            wf1[c][kt] = *(const short8*)(w1aT + ((size_t)((w * 4 + c) * 4 + kt) * 64 + lane) * 8);
    long wf2[16];
#pragma unroll
    for (int kt2 = 0; kt2 < 16; ++kt2)
        wf2[kt2] = w2T8[(size_t)(kt2 * 8 + w) * 64 + lane];

    // ---- init own z slice (u-layout: rows rs*16+m, cols jcol..jcol+3) ----
    float zr[4][4];
    float part = 0.f;
#pragma unroll
    for (int rs = 0; rs < 4; ++rs) {
        f32x4 e = *(const f32x4*)(eps0 + (size_t)(rowbase + rs * 16 + m) * NZ + jcol);
        short4v zb;
#pragma unroll
        for (int i = 0; i < 4; ++i) { zr[rs][i] = s0 * e[i]; zb[i] = f2bf(zr[rs][i]); }
        *(short4v*)(zu + rs * 4096 + zw_off) = zb;
    }
    __syncthreads();   // A (initial)

#pragma unroll 1
    for (int t = 0; t < NT; ++t) {
        // ---- GEMM1 (bf16, weights in regs): 2 chunks of 2 ROWSETS ----
        // Each z-frag read exactly once; 4:1 MFMA:LDS-read ratio.
#pragma unroll
        for (int rr = 0; rr < 2; ++rr) {
            f32x4 g1[4][2];
#pragma unroll
            for (int c = 0; c < 4; ++c)
#pragma unroll
                for (int r2 = 0; r2 < 2; ++r2) g1[c][r2] = zero;
#pragma unroll
            for (int kt = 0; kt < 4; ++kt) {
                short8 zb[2];
#pragma unroll
                for (int r2 = 0; r2 < 2; ++r2)
                    zb[r2] = *(const short8*)(zu + (rr * 2 + r2) * 4096 + (zu_base ^ (kt << 6)));
#pragma unroll
                for (int c = 0; c < 4; ++c)
#pragma unroll
                    for (int r2 = 0; r2 < 2; ++r2)
                        g1[c][r2] = __builtin_amdgcn_mfma_f32_16x16x32_bf16(
                            wf1[c][kt], zb[r2], g1[c][r2], 0, 0, 0);
            }
#pragma unroll
            for (int c = 0; c < 4; ++c) {
                // paired-kt2 granule address for h-tile ht=4w+c (round-3/4 verified)
                int Gc = (((w * 4 + ((c & 1) << 1) + (quad >> 1)) ^ m) << 4)
                       + (((c >> 1) & 1) << 3);
                f32x4 te = *(const f32x4*)(t_emb + (size_t)t * NHID + (w * 4 + c) * 16 + quad * 4);
#pragma unroll
                for (int r2 = 0; r2 < 2; ++r2) {
                    int rs = rr * 2 + r2;
                    float p0 = fmaxf(g1[c][r2][0] + bf2f(cbr[c][rs][0]) + te[0], 0.f);
                    float p1 = fmaxf(g1[c][r2][1] + bf2f(cbr[c][rs][1]) + te[1], 0.f);
                    float p2 = fmaxf(g1[c][r2][2] + bf2f(cbr[c][rs][2]) + te[2], 0.f);
                    float p3 = fmaxf(g1[c][r2][3] + bf2f(cbr[c][rs][3]) + te[3], 0.f);
                    int pk = __builtin_amdgcn_cvt_pk_fp8_f32(p0, p1, 0, false);
                    pk = __builtin_amdgcn_cvt_pk_fp8_f32(p2, p3, pk, true);
                    *(int*)(hidb + rs * 8192 + hw_base + Gc) = pk;
                }
            }
        }
        __syncthreads();   // B: hid ready

        // eps prefetch (u-layout rows) — latency hides under GEMM2
        f32x4 ef[4];
        {
            const float* ept = eps + (size_t)t * NB * NZ + (size_t)rowbase * NZ + jcol;
#pragma unroll
            for (int rs = 0; rs < 4; ++rs)
                ef[rs] = *(const f32x4*)(ept + (size_t)(rs * 16 + m) * NZ);
        }
        f32x4 sca = *(const f32x4*)(scb + t * 8);
        float c1mb = scb[t * 8 + 4];

        // ---- GEMM2 fused with EW per rowset-PAIR: ua liveness 16->8 regs,
        //      pair rp's EW VALU overlaps next pair's MFMAs ----
#pragma unroll
        for (int rp = 0; rp < 2; ++rp) {
            f32x4 ua[2];
            ua[0] = zero; ua[1] = zero;
#pragma unroll
            for (int kp = 0; kp < 8; ++kp) {
                long wlo = wf2[kp * 2];
                long whi = wf2[kp * 2 + 1];
                int go = ((kp * 4 + quad) ^ m) << 4;
#pragma unroll
                for (int r2 = 0; r2 < 2; ++r2) {
                    int rs = rp * 2 + r2;
                    long2v h2 = *(const long2v*)(hidb + rs * 8192 + hr_base + go);
                    ua[r2] = __builtin_amdgcn_mfma_f32_16x16x32_fp8_fp8(wlo, h2[0], ua[r2], 0, 0, 0);
                    ua[r2] = __builtin_amdgcn_mfma_f32_16x16x32_fp8_fp8(whi, h2[1], ua[r2], 0, 0, 0);
                }
            }
            // EW for this pair (round-5 math, verbatim)
#pragma unroll
            for (int r2 = 0; r2 < 2; ++r2) {
                int rs = rp * 2 + r2;
                short4v zb;
#pragma unroll
                for (int i = 0; i < 4; ++i) {
                    float z = zr[rs][i];
                    float e = ef[rs][i];
                    float uu = ua[r2][i] + b2r[i];
                    float mu_f = z + (sca[0] * z + uu) * dt;
                    float zn = mu_f + sca[1] * e;
                    float d = (z - zn * c1mb) * sca[2];
                    part += -0.5f * d * d + 0.5f * e * e + sca[3];
                    zr[rs][i] = zn;
                    zb[i] = f2bf(zn);
                }
                *(short4v*)(zu + rs * 4096 + zw_off) = zb;
            }
        }
        __syncthreads();   // A: z published for next step
    }

    // ---- terminal + prior correction: (z0/s0) == eps0 exactly ----
#pragma unroll
    for (int rs = 0; rs < 4; ++rs) {
        const float* ep = eps0 + (size_t)(rowbase + rs * 16 + m) * NZ + jcol;
        const float* tp = target_mu + (size_t)(rowbase + rs * 16 + m) * NZ + jcol;
        f32x4 a = *(const f32x4*)ep;
        f32x4 ta = *(const f32x4*)tp;
#pragma unroll
        for (int i = 0; i < 4; ++i) {
            float d0 = zr[rs][i] - ta[i];
            part += -0.5f * d0 * d0 + 0.5f * a[i] * a[i] + logs0;
        }
    }
#pragma unroll
    for (int off = 32; off >= 1; off >>= 1) part += __shfl_xor(part, off, 64);
    if (lane == 0) atomicAdd(out, part * (1.0f / NB));
}

extern "C" void kernel_launch(void* const* d_in, const int* in_sizes, int n_in,
                              void* d_out, int out_size, void* d_ws, size_t ws_size,
                              hipStream_t stream) {
    const float* ctx  = (const float*)d_in[0];
    const float* eps0 = (const float*)d_in[1];
    const float* eps  = (const float*)d_in[2];
    const float* beta = (const float*)d_in[3];
    const float* sig0 = (const float*)d_in[4];
    const float* W1   = (const float*)d_in[5];
    const float* b1   = (const float*)d_in[6];
    const float* W2   = (const float*)d_in[7];
    const float* b2   = (const float*)d_in[8];
    const float* temb = (const float*)d_in[9];
    const float* tmu  = (const float*)d_in[10];
    float* out = (float*)d_out;

    char* ws = (char*)d_ws;
    short* w1aT = (short*)ws;                  // 131072 B
    long*  w2T8 = (long*)(ws + 131072);        //  65536 B (fp8 frags)
    short* w1bT = (short*)(ws + 196608);       // 524288 B

    hipMemsetAsync(d_out, 0, sizeof(float), stream);
    pack_weights<<<768, 64, 0, stream>>>(W1, W2, w1aT, w2T8, w1bT);
    diffusion_main<<<256, 512, 0, stream>>>(eps0, eps, beta, sig0, ctx, b1, b2,
                                            temb, tmu, w1aT, w1bT, w2T8, out);
}

// Round 9
// 525.984 us; speedup vs baseline: 1.0350x; 1.0068x over previous
//
#include <hip/hip_runtime.h>
#include <hip/hip_bf16.h>

#define NB 16384
#define NZ 128
#define NH 512
#define NHID 512
#define NT 32

typedef __attribute__((ext_vector_type(8))) short short8;
typedef __attribute__((ext_vector_type(4))) short short4v;
typedef __attribute__((ext_vector_type(4))) float f32x4;
typedef __attribute__((ext_vector_type(2))) long long2v;

__device__ __forceinline__ short f2bf(float x) {
    union { __hip_bfloat16 h; short s; } u; u.h = __float2bfloat16(x); return u.s;
}
__device__ __forceinline__ float bf2f(short s) {
    union { unsigned int u; float f; } v; v.u = ((unsigned int)(unsigned short)s) << 16; return v.f;
}

// ---------------------------------------------------------------------------
// Prologue pack (REWRITTEN round 9 — same OUTPUT BYTES, coalesced loads):
//  w1aT  bf16 A-frags [ht(32)][kt(4)]   (128 frags x 1KB)
//  w2T8  fp8  A-frags [kt2(16)][jt(8)]  (128 frags x 512B)
//  w1bT  bf16 A-frags [ht(32)][kt(16)]  (512 frags x 1KB)
// A-frag 16x16x32: lane l holds A[m=l&15][k=(l>>4)*8+j], j=0..7.
//
// OLD pack: 8 scalar loads/lane at 2KB stride = 64 cache lines per load
// instruction, 3 waves/CU -> latency-bound scatter, O(100us) of the ~283us
// bench-minus-main overhead. NEW: stage the 32x16 f32 tile with coalesced
// 16B vector loads (lane i -> row i>>1, col-half (i&1)*8), transpose via
// [32][17]-padded LDS (pad kills the 4-way frag-read conflict; residual
// 2-way = free), emit identical frag bytes. Also folds the d_out memset
// into block 0 (one fewer dispatch; stream order precedes main's atomics).
// ---------------------------------------------------------------------------
__global__ __launch_bounds__(64) void pack_weights(const float* __restrict__ W1,
                                                   const float* __restrict__ W2,
                                                   short* __restrict__ w1aT,
                                                   long* __restrict__ w2T8,
                                                   short* __restrict__ w1bT,
                                                   float* __restrict__ out) {
    __shared__ float tile[32 * 17];
    int f = blockIdx.x;
    int l = threadIdx.x;
    int quad = l >> 4, m = l & 15;
    if (f == 0 && l == 0) *out = 0.f;   // folded memset

    // source-tile select (rows row0..row0+31, cols col0..col0+15)
    const float* src; int ld, row0, col0;
    if (f < 128) {                        // W1a^T : A[h][k]=W1[k][h], k<128
        int ht = f >> 2, kt = f & 3;
        src = W1; ld = NH; row0 = kt * 32; col0 = ht * 16;
    } else if (f < 256) {                 // W2^T fp8 : A[j][k=h]=W2[h][j]
        int g = f - 128; int kt2 = g >> 3, jt = g & 7;
        src = W2; ld = NZ; row0 = kt2 * 32; col0 = jt * 16;
    } else {                              // W1b^T : A[h][k]=W1[128+k][h]
        int g = f - 256; int ht = g >> 4, kt = g & 15;
        src = W1; ld = NH; row0 = 128 + kt * 32; col0 = ht * 16;
    }

    // coalesced stage: lane i -> row (i>>1), cols (i&1)*8 .. +7
    {
        int r = l >> 1, c8 = (l & 1) * 8;
        const float* p = src + (size_t)(row0 + r) * ld + col0 + c8;
        f32x4 a = *(const f32x4*)p;
        f32x4 b = *(const f32x4*)(p + 4);
#pragma unroll
        for (int j = 0; j < 4; ++j) {
            tile[r * 17 + c8 + j] = a[j];
            tile[r * 17 + c8 + 4 + j] = b[j];
        }
    }
    __syncthreads();

    // frag gather: v[j] = src[row0 + quad*8 + j][col0 + m]
    float v[8];
#pragma unroll
    for (int j = 0; j < 8; ++j) v[j] = tile[(quad * 8 + j) * 17 + m];

    if (f < 128) {
        short8 o;
#pragma unroll
        for (int j = 0; j < 8; ++j) o[j] = f2bf(v[j]);
        *(short8*)(w1aT + ((size_t)f * 64 + l) * 8) = o;
    } else if (f < 256) {
        int g = f - 128;
        int lo = __builtin_amdgcn_cvt_pk_fp8_f32(v[0], v[1], 0, false);
        lo = __builtin_amdgcn_cvt_pk_fp8_f32(v[2], v[3], lo, true);
        int hi = __builtin_amdgcn_cvt_pk_fp8_f32(v[4], v[5], 0, false);
        hi = __builtin_amdgcn_cvt_pk_fp8_f32(v[6], v[7], hi, true);
        long pv = ((long)(unsigned int)hi << 32) | (unsigned int)lo;
        w2T8[(size_t)g * 64 + l] = pv;
    } else {
        int g = f - 256;
        short8 o;
#pragma unroll
        for (int j = 0; j < 8; ++j) o[j] = f2bf(v[j]);
        *(short8*)(w1bT + ((size_t)g * 64 + l) * 8) = o;
    }
}

// ---------------------------------------------------------------------------
// Main: 256 blocks x 512 thr (8 waves), 64 rows/block. ROUND-5 VERBATIM
// (241us verified: paired-kt2 hid, rs-chunked GEMM1, reg-resident EW,
// 2 barriers). Rounds 6/7/8 all failed to beat it:
//  - EW-MICRO-OPT LAW (r6/7): no inline-asm cvt_pk, no persistent extra
//    accumulators; both lost 14-34us at the register cliff.
//  - FUSION LAW (r8): GEMM2+EW per-pair fusion neutral (+5); the scheduler
//    already overlaps the phases.
//  - REGISTER-CLIFF LAW (r1/3): 128-arch-VGPR limit; never extend liveness
//    across a GEMM phase; never launch_bounds(,4).
//  - OCCUPANCY pinned at 2 waves/SIMD (r2): arch(128)+AGPR(64, prologue
//    pacc) = 192 regs -> 2/SIMD; 8-wave blocks quantize next step at 4/SIMD
//    which needs <=128 total. Grid games don't move it.
// LDS 49KB: zu[4][16][256B] bf16 z | hid[4][16][512B] fp8 paired-kt2 |
// sconst[32][8]f32. Spill guard: FETCH ~165.5MB, WRITE ~5.2MB.
// ---------------------------------------------------------------------------
__global__ __launch_bounds__(512, 2) void diffusion_main(
    const float* __restrict__ eps0, const float* __restrict__ eps,
    const float* __restrict__ beta, const float* __restrict__ sigma0,
    const float* __restrict__ ctx, const float* __restrict__ b1,
    const float* __restrict__ b2, const float* __restrict__ t_emb,
    const float* __restrict__ target_mu,
    const short* __restrict__ w1aT, const short* __restrict__ w1bT,
    const long* __restrict__ w2T8, float* __restrict__ out)
{
    __shared__ alignas(16) char lds[50176];
    char* zu = lds;                      // 16 KB
    char* hidb = lds + 16384;            // 32 KB
    float* scb = (float*)(lds + 49152);  // 1 KB step constants
    const int w = threadIdx.x >> 6;
    const int lane = threadIdx.x & 63;
    const int quad = lane >> 4;
    const int m = lane & 15;
    const int swz = m & 7;
    const int rowbase = blockIdx.x * 64;
    const int jcol = w * 16 + quad * 4;  // this lane's u/z columns (EW layout)
    const float dt = 1.0f / 32.0f;
    const float s0 = sigma0[0];
    const float logs0 = logf(s0);
    const f32x4 zero = {0.f, 0.f, 0.f, 0.f};

    // XOR-swizzle address bases (per-lane constants)
    const int zu_base = m * 256 + ((quad ^ swz) << 4);   // GEMM1 z read: ^ (kt<<6), +rs*4096
    const int hw_base = m * 512 + ((quad & 1) << 2);     // hid write: + Gc, +rs*8192
    const int hr_base = m * 512;                         // hid read: +((4kp+quad)^m)<<4, +rs*8192
    const int zw_off  = m * 256 + ((((w << 1) + (quad >> 1)) ^ swz) << 4)
                      + ((quad & 1) << 3);               // EW z write (u-layout), +rs*4096

    // step constants (round-5 layout):
    // [0]=beta_f  [1]=sf  [2]=1/sb  [3]=0.5*(ln bf - ln bb)  [4]=1-bb*dt
    if (threadIdx.x < 32) {
        int t = threadIdx.x;
        float bfv = beta[t];
        float bbv = beta[(t + 31) & 31];
        float sf = sqrtf(2.f * bfv * dt) * s0;
        float sb = sqrtf(2.f * bbv * dt) * s0;
        scb[t * 8 + 0] = bfv;
        scb[t * 8 + 1] = sf;
        scb[t * 8 + 2] = 1.f / sb;
        scb[t * 8 + 3] = 0.5f * (logf(bfv) - logf(bbv));
        scb[t * 8 + 4] = 1.f - bbv * dt;
    }

    // ---- prologue: cbr[c][rs] = (ctx @ W1b + b1), this wave's 4 h-tiles ----
    f32x4 pacc[4][4];
#pragma unroll
    for (int c = 0; c < 4; ++c)
#pragma unroll
        for (int rs = 0; rs < 4; ++rs) pacc[c][rs] = zero;
#pragma unroll 4
    for (int kt = 0; kt < 16; ++kt) {
        short8 cf[4];
#pragma unroll
        for (int rs = 0; rs < 4; ++rs) {
            const float* cp = ctx + (size_t)(rowbase + rs * 16 + m) * NH + kt * 32 + quad * 8;
            f32x4 a = *(const f32x4*)cp;
            f32x4 b = *(const f32x4*)(cp + 4);
            short8 tt;
#pragma unroll
            for (int j = 0; j < 4; ++j) { tt[j] = f2bf(a[j]); tt[4 + j] = f2bf(b[j]); }
            cf[rs] = tt;
        }
#pragma unroll
        for (int c = 0; c < 4; ++c) {
            short8 af = *(const short8*)(w1bT + ((size_t)((w * 4 + c) * 16 + kt) * 64 + lane) * 8);
#pragma unroll
            for (int rs = 0; rs < 4; ++rs)
                pacc[c][rs] = __builtin_amdgcn_mfma_f32_16x16x32_bf16(af, cf[rs], pacc[c][rs], 0, 0, 0);
        }
    }
    short4v cbr[4][4];
#pragma unroll
    for (int c = 0; c < 4; ++c) {
        f32x4 bv = *(const f32x4*)(b1 + (w * 4 + c) * 16 + quad * 4);
#pragma unroll
        for (int rs = 0; rs < 4; ++rs) {
            short4v o;
#pragma unroll
            for (int i = 0; i < 4; ++i) o[i] = f2bf(pacc[c][rs][i] + bv[i]);
            cbr[c][rs] = o;
        }
    }
    f32x4 b2r = *(const f32x4*)(b2 + jcol);  // b2 for this lane's EW columns

    // ---- persistent weights into registers ----
    short8 wf1[4][4];
#pragma unroll
    for (int c = 0; c < 4; ++c)
#pragma unroll
        for (int kt = 0; kt < 4; ++kt)
            wf1[c][kt] = *(const short8*)(w1aT + ((size_t)((w * 4 + c) * 4 + kt) * 64 + lane) * 8);
    long wf2[16];
#pragma unroll
    for (int kt2 = 0; kt2 < 16; ++kt2)
        wf2[kt2] = w2T8[(size_t)(kt2 * 8 + w) * 64 + lane];

    // ---- init own z slice (u-layout: rows rs*16+m, cols jcol..jcol+3) ----
    float zr[4][4];
    float part = 0.f;
#pragma unroll
    for (int rs = 0; rs < 4; ++rs) {
        f32x4 e = *(const f32x4*)(eps0 + (size_t)(rowbase + rs * 16 + m) * NZ + jcol);
        short4v zb;
#pragma unroll
        for (int i = 0; i < 4; ++i) { zr[rs][i] = s0 * e[i]; zb[i] = f2bf(zr[rs][i]); }
        *(short4v*)(zu + rs * 4096 + zw_off) = zb;
    }
    __syncthreads();   // A (initial)

#pragma unroll 1
    for (int t = 0; t < NT; ++t) {
        // ---- GEMM1 (bf16, weights in regs): 2 chunks of 2 ROWSETS ----
        // Each z-frag read exactly once; 4:1 MFMA:LDS-read ratio.
#pragma unroll
        for (int rr = 0; rr < 2; ++rr) {
            f32x4 g1[4][2];
#pragma unroll
            for (int c = 0; c < 4; ++c)
#pragma unroll
                for (int r2 = 0; r2 < 2; ++r2) g1[c][r2] = zero;
#pragma unroll
            for (int kt = 0; kt < 4; ++kt) {
                short8 zb[2];
#pragma unroll
                for (int r2 = 0; r2 < 2; ++r2)
                    zb[r2] = *(const short8*)(zu + (rr * 2 + r2) * 4096 + (zu_base ^ (kt << 6)));
#pragma unroll
                for (int c = 0; c < 4; ++c)
#pragma unroll
                    for (int r2 = 0; r2 < 2; ++r2)
                        g1[c][r2] = __builtin_amdgcn_mfma_f32_16x16x32_bf16(
                            wf1[c][kt], zb[r2], g1[c][r2], 0, 0, 0);
            }
#pragma unroll
            for (int c = 0; c < 4; ++c) {
                // paired-kt2 granule address for h-tile ht=4w+c (round-3/4 verified)
                int Gc = (((w * 4 + ((c & 1) << 1) + (quad >> 1)) ^ m) << 4)
                       + (((c >> 1) & 1) << 3);
                f32x4 te = *(const f32x4*)(t_emb + (size_t)t * NHID + (w * 4 + c) * 16 + quad * 4);
#pragma unroll
                for (int r2 = 0; r2 < 2; ++r2) {
                    int rs = rr * 2 + r2;
                    float p0 = fmaxf(g1[c][r2][0] + bf2f(cbr[c][rs][0]) + te[0], 0.f);
                    float p1 = fmaxf(g1[c][r2][1] + bf2f(cbr[c][rs][1]) + te[1], 0.f);
                    float p2 = fmaxf(g1[c][r2][2] + bf2f(cbr[c][rs][2]) + te[2], 0.f);
                    float p3 = fmaxf(g1[c][r2][3] + bf2f(cbr[c][rs][3]) + te[3], 0.f);
                    int pk = __builtin_amdgcn_cvt_pk_fp8_f32(p0, p1, 0, false);
                    pk = __builtin_amdgcn_cvt_pk_fp8_f32(p2, p3, pk, true);
                    *(int*)(hidb + rs * 8192 + hw_base + Gc) = pk;
                }
            }
        }
        __syncthreads();   // B: hid ready

        // eps prefetch (u-layout rows) — latency hides under GEMM2
        f32x4 ef[4];
        {
            const float* ept = eps + (size_t)t * NB * NZ + (size_t)rowbase * NZ + jcol;
#pragma unroll
            for (int rs = 0; rs < 4; ++rs)
                ef[rs] = *(const f32x4*)(ept + (size_t)(rs * 16 + m) * NZ);
        }
        f32x4 sca = *(const f32x4*)(scb + t * 8);
        float c1mb = scb[t * 8 + 4];

        // ---- GEMM2 (fp8, weights in regs): j-tile jt=w, paired-kt2 b128 reads ----
        f32x4 ua[4];
#pragma unroll
        for (int rs = 0; rs < 4; ++rs) ua[rs] = zero;
#pragma unroll
        for (int kp = 0; kp < 8; ++kp) {
            long wlo = wf2[kp * 2];
            long whi = wf2[kp * 2 + 1];
            int go = ((kp * 4 + quad) ^ m) << 4;
#pragma unroll
            for (int rs = 0; rs < 4; ++rs) {
                long2v h2 = *(const long2v*)(hidb + rs * 8192 + hr_base + go);
                ua[rs] = __builtin_amdgcn_mfma_f32_16x16x32_fp8_fp8(wlo, h2[0], ua[rs], 0, 0, 0);
                ua[rs] = __builtin_amdgcn_mfma_f32_16x16x32_fp8_fp8(whi, h2[1], ua[rs], 0, 0, 0);
            }
        }

        // ---- elementwise, fully in registers (u = ua + b2); no barrier C ----
#pragma unroll
        for (int rs = 0; rs < 4; ++rs) {
            short4v zb;
#pragma unroll
            for (int i = 0; i < 4; ++i) {
                float z = zr[rs][i];
                float e = ef[rs][i];
                float uu = ua[rs][i] + b2r[i];
                float mu_f = z + (sca[0] * z + uu) * dt;
                float zn = mu_f + sca[1] * e;
                float d = (z - zn * c1mb) * sca[2];
                part += -0.5f * d * d + 0.5f * e * e + sca[3];
                zr[rs][i] = zn;
                zb[i] = f2bf(zn);
            }
            *(short4v*)(zu + rs * 4096 + zw_off) = zb;
        }
        __syncthreads();   // A: z published for next step
    }

    // ---- terminal + prior correction: (z0/s0) == eps0 exactly ----
#pragma unroll
    for (int rs = 0; rs < 4; ++rs) {
        const float* ep = eps0 + (size_t)(rowbase + rs * 16 + m) * NZ + jcol;
        const float* tp = target_mu + (size_t)(rowbase + rs * 16 + m) * NZ + jcol;
        f32x4 a = *(const f32x4*)ep;
        f32x4 ta = *(const f32x4*)tp;
#pragma unroll
        for (int i = 0; i < 4; ++i) {
            float d0 = zr[rs][i] - ta[i];
            part += -0.5f * d0 * d0 + 0.5f * a[i] * a[i] + logs0;
        }
    }
#pragma unroll
    for (int off = 32; off >= 1; off >>= 1) part += __shfl_xor(part, off, 64);
    if (lane == 0) atomicAdd(out, part * (1.0f / NB));
}

extern "C" void kernel_launch(void* const* d_in, const int* in_sizes, int n_in,
                              void* d_out, int out_size, void* d_ws, size_t ws_size,
                              hipStream_t stream) {
    const float* ctx  = (const float*)d_in[0];
    const float* eps0 = (const float*)d_in[1];
    const float* eps  = (const float*)d_in[2];
    const float* beta = (const float*)d_in[3];
    const float* sig0 = (const float*)d_in[4];
    const float* W1   = (const float*)d_in[5];
    const float* b1   = (const float*)d_in[6];
    const float* W2   = (const float*)d_in[7];
    const float* b2   = (const float*)d_in[8];
    const float* temb = (const float*)d_in[9];
    const float* tmu  = (const float*)d_in[10];
    float* out = (float*)d_out;

    char* ws = (char*)d_ws;
    short* w1aT = (short*)ws;                  // 131072 B
    long*  w2T8 = (long*)(ws + 131072);        //  65536 B (fp8 frags)
    short* w1bT = (short*)(ws + 196608);       // 524288 B

    // memset folded into pack_weights (block 0 zeroes out before main runs)
    pack_weights<<<768, 64, 0, stream>>>(W1, W2, w1aT, w2T8, w1bT, out);
    diffusion_main<<<256, 512, 0, stream>>>(eps0, eps, beta, sig0, ctx, b1, b2,
                                            temb, tmu, w1aT, w1bT, w2T8, out);
}